// Round 6
// baseline (107.398 us; speedup 1.0000x reference)
//
#include <hip/hip_runtime.h>

// FineMatching fused v3b (v3 with compile fix: nontemporal builtins need
// native clang vectors, not HIP_vector_type — use ext_vector_type(4)).
// One block per proposal (512 x 512 threads).
// - Tile data lives in REGISTERS (8 x float4/thread) end-to-end; the 64 KB
//   XOR-swizzled LDS tile is only a transpose buffer for the col scan.
// - top-3 insert via v_med3_f32: 3 VALU/insert (vs ~9 cndmask-chain).
// - Row thirds fused into the load (in-wave shfl merge, consumed in-thread).
// - Col thirds stashed in LDS (reused tile space) -> no global ws round-trip.
// - Non-temporal loads/stores on all single-touch streams.
// d_out = [score_map (P*R*S), corr_map (P*R*S)] f32.

typedef float  vf4 __attribute__((ext_vector_type(4)));
typedef int    vi4 __attribute__((ext_vector_type(4)));

constexpr int NP = 512;
constexpr int NR = 128;
constexpr int NS = 128;
constexpr int RS = NR * NS;          // 16384 floats = 64 KB
constexpr float THRESHOLD = 0.05f;
constexpr float NEG_INF = -3.4e38f;

__device__ __forceinline__ void top3_insert(float v, float& m0, float& m1, float& m2) {
    // 3 VALU: v_max + 2x v_med3 (sorted m0>=m1>=m2 invariant)
    float n1 = __builtin_amdgcn_fmed3f(v, m0, m1);
    float n2 = __builtin_amdgcn_fmed3f(v, m1, m2);
    m0 = fmaxf(m0, v);
    m1 = n1; m2 = n2;
}

__device__ __forceinline__ void shfl_merge3(int d, float& m0, float& m1, float& m2) {
    float o0 = __shfl_xor(m0, d);
    float o1 = __shfl_xor(m1, d);
    float o2 = __shfl_xor(m2, d);
    top3_insert(o0, m0, m1, m2);
    top3_insert(o1, m0, m1, m2);
    top3_insert(o2, m0, m1, m2);
}

__global__ __launch_bounds__(512, 4) void fused_kernel(
    const float* __restrict__ in,     // [P,R,S] raw log-scores
    const int*   __restrict__ rmask,  // [P,R]
    const int*   __restrict__ smask,  // [P,S]
    const float* __restrict__ ncs,    // [P]
    float*       __restrict__ out)    // [2,P,R,S]
{
    __shared__ vf4 tile4[RS / 4];     // 64 KB, XOR-swizzled; reused for col thirds
    const int p   = blockIdx.x;
    const int t   = threadIdx.x;
    const int row = t >> 2;           // this thread's row
    const int q   = t & 3;            // quarter within row

    const vf4* b4 = (const vf4*)(in + (size_t)p * RS);

    // ---- Phase 1: nt-load into REGISTERS (coalesced: 16 rows x 64B/instr),
    //      swizzled LDS store (conflict-free), row top-3 on the fly.
    vf4 x[8];
    float r0 = NEG_INF, r1 = NEG_INF, r2 = NEG_INF;
    #pragma unroll
    for (int j = 0; j < 8; ++j) {
        int c4 = q + 4 * j;
        x[j] = __builtin_nontemporal_load(&b4[row * 32 + c4]);
        tile4[row * 32 + (c4 ^ (row & 31))] = x[j];
        top3_insert(x[j].x, r0, r1, r2);
        top3_insert(x[j].y, r0, r1, r2);
        top3_insert(x[j].z, r0, r1, r2);
        top3_insert(x[j].w, r0, r1, r2);
    }
    shfl_merge3(1, r0, r1, r2);       // merge quarter-group (lanes 4r..4r+3)
    shfl_merge3(2, r0, r1, r2);
    const float tr = r2;              // row third — stays in this thread
    __syncthreads();

    // ---- Phase 2: col top-3 from swizzled tile. col=t>>2, seg=t&3,
    //      row order r = 4*seg + (i&3) + 16*(i>>2) -> 2-way bank aliasing (free).
    float c2_third;
    {
        const int col = t >> 2, seg = t & 3;
        const int c4c = col >> 2, cw = col & 3;
        const float* tf = (const float*)tile4;
        float c0 = NEG_INF, c1 = NEG_INF, c2 = NEG_INF;
        #pragma unroll 8
        for (int i = 0; i < 32; ++i) {
            int r = 4 * seg + (i & 3) + 16 * (i >> 2);
            top3_insert(tf[r * 128 + ((c4c ^ (r & 31)) << 2) + cw], c0, c1, c2);
        }
        shfl_merge3(1, c0, c1, c2);   // merge segs (lanes 4c..4c+3)
        shfl_merge3(2, c0, c1, c2);
        c2_third = c2;
    }
    __syncthreads();                  // all col-scan LDS reads done
    {
        float* thirds = (float*)tile4;      // reuse first 512 B of tile
        if ((t & 3) == 0) thirds[t >> 2] = c2_third;
    }
    __syncthreads();                  // thirds visible block-wide

    // ---- Phase 3: epilogue from registers; tc from LDS (4 addrs/wave,
    //      distinct banks -> broadcast, conflict-free); nt streaming stores.
    const float* thirds = (const float*)tile4;
    const float halfnc = 0.5f * ncs[p];
    const float mrf    = (rmask[p * NR + row] != 0) ? 1.0f : 0.0f;
    vf4* sc4 = (vf4*)(out + (size_t)p * RS);
    vf4* co4 = (vf4*)(out + (size_t)(NP + p) * RS);
    const vi4* sm4 = (const vi4*)(smask + (size_t)p * NS);

    #pragma unroll
    for (int j = 0; j < 8; ++j) {
        int c4 = q + 4 * j;
        vf4 tc = ((const vf4*)thirds)[c4];
        vi4 ms = __builtin_nontemporal_load(&sm4[c4]);
        vf4 v  = x[j];
        vf4 sc, co;

        {   float e = __expf(v.x);
            float w = ((v.x >= tr) ? halfnc : 0.f) + ((v.x >= tc.x) ? halfnc : 0.f);
            sc.x = e * w;
            float mk = (ms.x != 0) ? mrf : 0.f;
            co.x = (e > THRESHOLD && w > 0.f) ? mk : 0.f; }
        {   float e = __expf(v.y);
            float w = ((v.y >= tr) ? halfnc : 0.f) + ((v.y >= tc.y) ? halfnc : 0.f);
            sc.y = e * w;
            float mk = (ms.y != 0) ? mrf : 0.f;
            co.y = (e > THRESHOLD && w > 0.f) ? mk : 0.f; }
        {   float e = __expf(v.z);
            float w = ((v.z >= tr) ? halfnc : 0.f) + ((v.z >= tc.z) ? halfnc : 0.f);
            sc.z = e * w;
            float mk = (ms.z != 0) ? mrf : 0.f;
            co.z = (e > THRESHOLD && w > 0.f) ? mk : 0.f; }
        {   float e = __expf(v.w);
            float w = ((v.w >= tr) ? halfnc : 0.f) + ((v.w >= tc.w) ? halfnc : 0.f);
            sc.w = e * w;
            float mk = (ms.w != 0) ? mrf : 0.f;
            co.w = (e > THRESHOLD && w > 0.f) ? mk : 0.f; }

        __builtin_nontemporal_store(sc, &sc4[row * 32 + c4]);
        __builtin_nontemporal_store(co, &co4[row * 32 + c4]);
    }
}

extern "C" void kernel_launch(void* const* d_in, const int* in_sizes, int n_in,
                              void* d_out, int out_size, void* d_ws, size_t ws_size,
                              hipStream_t stream) {
    const float* msm   = (const float*)d_in[0];  // [P,R,S] f32
    const int*   rmask = (const int*)  d_in[1];  // [P,R]
    const int*   smask = (const int*)  d_in[2];  // [P,S]
    const float* ncs   = (const float*)d_in[3];  // [P]
    float* out = (float*)d_out;

    fused_kernel<<<NP, 512, 0, stream>>>(msm, rmask, smask, ncs, out);
}

// Round 7
// 102.195 us; speedup vs baseline: 1.0509x; 1.0509x over previous
//
#include <hip/hip_runtime.h>

// FineMatching fused v4: LDS-free single-kernel, ONE barrier.
// One block per proposal (512 blocks x 512 threads).
// Phase A: col top-3 read DIRECTLY from global (64B-granular coalesced;
//          4 threads/col in-wave, med3 inserts, shfl merges) -> 512 B LDS.
// Phase B: row-chunk re-read (fully coalesced, L2-hot: block's 64 KB was
//          just fetched) with row top-3 fused into the load; tr never
//          leaves the consuming thread. Epilogue + coalesced stores.
// No LDS tile, no ws round-trip, no spill (x[8] held only across 2 shfls).
// d_out = [score_map (P*R*S), corr_map (P*R*S)] f32.

typedef float vf4 __attribute__((ext_vector_type(4)));
typedef int   vi4 __attribute__((ext_vector_type(4)));

constexpr int NP = 512;
constexpr int NR = 128;
constexpr int NS = 128;
constexpr int RS = NR * NS;          // 16384
constexpr float THRESHOLD = 0.05f;
constexpr float NEG_INF = -3.4e38f;

__device__ __forceinline__ void top3_insert(float v, float& m0, float& m1, float& m2) {
    // 3 VALU: v_max + 2x v_med3 (sorted m0>=m1>=m2 invariant)
    float n1 = __builtin_amdgcn_fmed3f(v, m0, m1);
    float n2 = __builtin_amdgcn_fmed3f(v, m1, m2);
    m0 = fmaxf(m0, v);
    m1 = n1; m2 = n2;
}

__device__ __forceinline__ void shfl_merge3(int d, float& m0, float& m1, float& m2) {
    float o0 = __shfl_xor(m0, d);
    float o1 = __shfl_xor(m1, d);
    float o2 = __shfl_xor(m2, d);
    top3_insert(o0, m0, m1, m2);
    top3_insert(o1, m0, m1, m2);
    top3_insert(o2, m0, m1, m2);
}

__global__ __launch_bounds__(512, 4) void fused_kernel(
    const float* __restrict__ in,     // [P,R,S] raw log-scores
    const int*   __restrict__ rmask,  // [P,R]
    const int*   __restrict__ smask,  // [P,S]
    const float* __restrict__ ncs,    // [P]
    float*       __restrict__ out)    // [2,P,R,S]
{
    __shared__ float thirds[NS];      // col thirds only — 512 B
    const int p = blockIdx.x;
    const int t = threadIdx.x;
    const float* base = in + (size_t)p * RS;

    // ---- Phase A: col top-3 from global. col = t>>2 (4 lanes/col, in-wave),
    //      seg = t&3, rows r = seg + 4i. Per instr: 16 consecutive cols x 4
    //      rows = 4 x 64B chunks; all lines fully consumed across the loop.
    {
        const int col = t >> 2, seg = t & 3;
        const float* cbase = base + col + seg * NS;
        float c0 = NEG_INF, c1 = NEG_INF, c2 = NEG_INF;
        #pragma unroll 8
        for (int i = 0; i < 32; ++i)
            top3_insert(cbase[i * 4 * NS], c0, c1, c2);
        shfl_merge3(1, c0, c1, c2);   // merge segs (lanes 4c..4c+3)
        shfl_merge3(2, c0, c1, c2);
        if (seg == 0) thirds[col] = c2;
    }
    __syncthreads();                  // the only barrier

    // ---- Phase B: row top-3 fused into coalesced re-load (L2-hot),
    //      then epilogue. row = t>>2, q = t&3, chunks c4 = q + 4j.
    const int row = t >> 2, q = t & 3;
    const vf4* b4 = (const vf4*)base;
    vf4 x[8];
    float r0 = NEG_INF, r1 = NEG_INF, r2 = NEG_INF;
    #pragma unroll
    for (int j = 0; j < 8; ++j) {
        x[j] = b4[row * 32 + (q + 4 * j)];
        top3_insert(x[j].x, r0, r1, r2);
        top3_insert(x[j].y, r0, r1, r2);
        top3_insert(x[j].z, r0, r1, r2);
        top3_insert(x[j].w, r0, r1, r2);
    }
    shfl_merge3(1, r0, r1, r2);       // merge quarter-group (lanes 4r..4r+3)
    shfl_merge3(2, r0, r1, r2);
    const float tr = r2;              // row third — consumed by this thread

    const float halfnc = 0.5f * ncs[p];
    const float mrf    = (rmask[p * NR + row] != 0) ? 1.0f : 0.0f;
    vf4* sc4 = (vf4*)(out + (size_t)p * RS);
    vf4* co4 = (vf4*)(out + (size_t)(NP + p) * RS);
    const vi4* sm4 = (const vi4*)(smask + (size_t)p * NS);
    const vf4* th4 = (const vf4*)thirds;

    #pragma unroll
    for (int j = 0; j < 8; ++j) {
        int c4 = q + 4 * j;
        vf4 tc = th4[c4];             // 4 addrs/wave, distinct banks -> broadcast
        vi4 ms = sm4[c4];
        vf4 v  = x[j];
        vf4 sc, co;

        {   float e = __expf(v.x);
            float w = ((v.x >= tr) ? halfnc : 0.f) + ((v.x >= tc.x) ? halfnc : 0.f);
            sc.x = e * w;
            float mk = (ms.x != 0) ? mrf : 0.f;
            co.x = (e > THRESHOLD && w > 0.f) ? mk : 0.f; }
        {   float e = __expf(v.y);
            float w = ((v.y >= tr) ? halfnc : 0.f) + ((v.y >= tc.y) ? halfnc : 0.f);
            sc.y = e * w;
            float mk = (ms.y != 0) ? mrf : 0.f;
            co.y = (e > THRESHOLD && w > 0.f) ? mk : 0.f; }
        {   float e = __expf(v.z);
            float w = ((v.z >= tr) ? halfnc : 0.f) + ((v.z >= tc.z) ? halfnc : 0.f);
            sc.z = e * w;
            float mk = (ms.z != 0) ? mrf : 0.f;
            co.z = (e > THRESHOLD && w > 0.f) ? mk : 0.f; }
        {   float e = __expf(v.w);
            float w = ((v.w >= tr) ? halfnc : 0.f) + ((v.w >= tc.w) ? halfnc : 0.f);
            sc.w = e * w;
            float mk = (ms.w != 0) ? mrf : 0.f;
            co.w = (e > THRESHOLD && w > 0.f) ? mk : 0.f; }

        sc4[row * 32 + c4] = sc;
        co4[row * 32 + c4] = co;
    }
}

extern "C" void kernel_launch(void* const* d_in, const int* in_sizes, int n_in,
                              void* d_out, int out_size, void* d_ws, size_t ws_size,
                              hipStream_t stream) {
    const float* msm   = (const float*)d_in[0];  // [P,R,S] f32
    const int*   rmask = (const int*)  d_in[1];  // [P,R]
    const int*   smask = (const int*)  d_in[2];  // [P,S]
    const float* ncs   = (const float*)d_in[3];  // [P]
    float* out = (float*)d_out;

    fused_kernel<<<NP, 512, 0, stream>>>(msm, rmask, smask, ncs, out);
}

// Round 8
// 97.848 us; speedup vs baseline: 1.0976x; 1.0444x over previous
//
#include <hip/hip_runtime.h>

// FineMatching fused v5 (= R4 structure + register-resident epilogue).
// One block per proposal (512 blocks x 512 threads), 64 KB XOR-swizzled LDS
// tile used ONLY by the col scan; epilogue data stays in registers (x[8]).
// Col thirds go through a separate 512 B LDS array (no global ws, no fence).
// __launch_bounds__(512,2): 256-VGPR cap -> no spill (R6's regression was
// the 128-cap spill + NT stores; both removed here).
// d_out = [score_map (P*R*S), corr_map (P*R*S)] f32.

typedef float vf4 __attribute__((ext_vector_type(4)));
typedef int   vi4 __attribute__((ext_vector_type(4)));

constexpr int NP = 512;
constexpr int NR = 128;
constexpr int NS = 128;
constexpr int RS = NR * NS;          // 16384 floats = 64 KB
constexpr float THRESHOLD = 0.05f;
constexpr float NEG_INF = -3.4e38f;

__device__ __forceinline__ void top3_insert(float v, float& m0, float& m1, float& m2) {
    // 3 VALU: v_max + 2x v_med3 (sorted m0>=m1>=m2 invariant)
    float n1 = __builtin_amdgcn_fmed3f(v, m0, m1);
    float n2 = __builtin_amdgcn_fmed3f(v, m1, m2);
    m0 = fmaxf(m0, v);
    m1 = n1; m2 = n2;
}

__device__ __forceinline__ void shfl_merge3(int d, float& m0, float& m1, float& m2) {
    float o0 = __shfl_xor(m0, d);
    float o1 = __shfl_xor(m1, d);
    float o2 = __shfl_xor(m2, d);
    top3_insert(o0, m0, m1, m2);
    top3_insert(o1, m0, m1, m2);
    top3_insert(o2, m0, m1, m2);
}

__global__ __launch_bounds__(512, 2) void fused_kernel(
    const float* __restrict__ in,     // [P,R,S] raw log-scores
    const int*   __restrict__ rmask,  // [P,R]
    const int*   __restrict__ smask,  // [P,S]
    const float* __restrict__ ncs,    // [P]
    float*       __restrict__ out)    // [2,P,R,S]
{
    __shared__ vf4   tile4[RS / 4];   // 64 KB, XOR-swizzled (col-scan transpose only)
    __shared__ float thirds[NS];      // col thirds — separate, no tile-reuse barrier
    const int p   = blockIdx.x;
    const int t   = threadIdx.x;
    const int row = t >> 2;           // this thread's row (load + epilogue)
    const int q   = t & 3;            // quarter within row

    const vf4* b4 = (const vf4*)(in + (size_t)p * RS);

    // ---- Phase 1: load into REGISTERS (coalesced: 16 rows x 64B/instr),
    //      swizzled LDS store (8 lanes/bank-group: conflict-free), row top-3
    //      on the fly.
    vf4 x[8];
    float r0 = NEG_INF, r1 = NEG_INF, r2 = NEG_INF;
    #pragma unroll
    for (int j = 0; j < 8; ++j) {
        int c4 = q + 4 * j;
        x[j] = b4[row * 32 + c4];
        tile4[row * 32 + (c4 ^ (row & 31))] = x[j];
        top3_insert(x[j].x, r0, r1, r2);
        top3_insert(x[j].y, r0, r1, r2);
        top3_insert(x[j].z, r0, r1, r2);
        top3_insert(x[j].w, r0, r1, r2);
    }
    shfl_merge3(1, r0, r1, r2);       // merge quarter-group (lanes 4r..4r+3)
    shfl_merge3(2, r0, r1, r2);
    const float tr = r2;              // row third — consumed by this same thread
    __syncthreads();                  // tile ready

    // ---- Phase 2: col top-3 from swizzled tile. col=t>>2, seg=t&3,
    //      row order r = 4*seg + (i&3) + 16*(i>>2) -> 2-way bank aliasing (free).
    {
        const int col = t >> 2, seg = t & 3;
        const int c4c = col >> 2, cw = col & 3;
        const float* tf = (const float*)tile4;
        float c0 = NEG_INF, c1 = NEG_INF, c2 = NEG_INF;
        #pragma unroll 8
        for (int i = 0; i < 32; ++i) {
            int r = 4 * seg + (i & 3) + 16 * (i >> 2);
            top3_insert(tf[r * 128 + ((c4c ^ (r & 31)) << 2) + cw], c0, c1, c2);
        }
        shfl_merge3(1, c0, c1, c2);   // merge segs (lanes 4c..4c+3)
        shfl_merge3(2, c0, c1, c2);
        if (seg == 0) thirds[col] = c2;
    }
    __syncthreads();                  // thirds ready

    // ---- Phase 3: epilogue from registers; tc from LDS (4 addrs/wave ->
    //      broadcast); coalesced float4 stores.
    const float halfnc = 0.5f * ncs[p];
    const float mrf    = (rmask[p * NR + row] != 0) ? 1.0f : 0.0f;
    vf4* sc4 = (vf4*)(out + (size_t)p * RS);
    vf4* co4 = (vf4*)(out + (size_t)(NP + p) * RS);
    const vi4* sm4 = (const vi4*)(smask + (size_t)p * NS);
    const vf4* th4 = (const vf4*)thirds;

    #pragma unroll
    for (int j = 0; j < 8; ++j) {
        int c4 = q + 4 * j;
        vf4 tc = th4[c4];
        vi4 ms = sm4[c4];
        vf4 v  = x[j];
        vf4 sc, co;

        {   float e = __expf(v.x);
            float w = ((v.x >= tr) ? halfnc : 0.f) + ((v.x >= tc.x) ? halfnc : 0.f);
            sc.x = e * w;
            float mk = (ms.x != 0) ? mrf : 0.f;
            co.x = (e > THRESHOLD && w > 0.f) ? mk : 0.f; }
        {   float e = __expf(v.y);
            float w = ((v.y >= tr) ? halfnc : 0.f) + ((v.y >= tc.y) ? halfnc : 0.f);
            sc.y = e * w;
            float mk = (ms.y != 0) ? mrf : 0.f;
            co.y = (e > THRESHOLD && w > 0.f) ? mk : 0.f; }
        {   float e = __expf(v.z);
            float w = ((v.z >= tr) ? halfnc : 0.f) + ((v.z >= tc.z) ? halfnc : 0.f);
            sc.z = e * w;
            float mk = (ms.z != 0) ? mrf : 0.f;
            co.z = (e > THRESHOLD && w > 0.f) ? mk : 0.f; }
        {   float e = __expf(v.w);
            float w = ((v.w >= tr) ? halfnc : 0.f) + ((v.w >= tc.w) ? halfnc : 0.f);
            sc.w = e * w;
            float mk = (ms.w != 0) ? mrf : 0.f;
            co.w = (e > THRESHOLD && w > 0.f) ? mk : 0.f; }

        sc4[row * 32 + c4] = sc;
        co4[row * 32 + c4] = co;
    }
}

extern "C" void kernel_launch(void* const* d_in, const int* in_sizes, int n_in,
                              void* d_out, int out_size, void* d_ws, size_t ws_size,
                              hipStream_t stream) {
    const float* msm   = (const float*)d_in[0];  // [P,R,S] f32
    const int*   rmask = (const int*)  d_in[1];  // [P,R]
    const int*   smask = (const int*)  d_in[2];  // [P,S]
    const float* ncs   = (const float*)d_in[3];  // [P]
    float* out = (float*)d_out;

    fused_kernel<<<NP, 512, 0, stream>>>(msm, rmask, smask, ncs, out);
}